// Round 2
// baseline (910.947 us; speedup 1.0000x reference)
//
#include <hip/hip_runtime.h>
#include <hip/hip_bf16.h>
#include <math.h>

#define B_    2
#define L_    512
#define HIN_  1024
#define ENT_  16
#define NE1_  17
#define D_    50
#define TOT_  850            // NE1_*D_
#define M_    (B_*L_)        // 1024
#define SCALE_ 0.14142135623730950488f  // 1/sqrt(50)

// ---------------- workspace layout (floats) ----------------
// S_t: [B][17][L][D]  start projections (rope applied to e<16 in-place)
// E_t: [B][17][L][D]  end projections
// cd : [B][511]       conj diagonal (includes scale)
// fm_part: [4 kc][B][L][L] partial mask reductions
#define OFF_S   ((size_t)0)
#define SZ_SE   ((size_t)B_*NE1_*L_*D_)          // 870400
#define OFF_E   (OFF_S + SZ_SE)
#define OFF_CD  (OFF_E + SZ_SE)
#define SZ_CD   ((size_t)1024)
#define OFF_FM  (OFF_CD + SZ_CD)
#define SZ_FM   ((size_t)4*B_*L_*L_)             // 2097152

// ---------------- Kernel A: projection GEMM ----------------
// C = X(1024x1024) @ W(1024x850) + bias, written as [b][e][l][d]
__global__ __launch_bounds__(256) void gemm_proj(
    const float* __restrict__ X,
    const float* __restrict__ Ws, const float* __restrict__ bs,
    const float* __restrict__ We, const float* __restrict__ be,
    float* __restrict__ S_t, float* __restrict__ E_t)
{
    const int mat = blockIdx.z;
    const float* __restrict__ W    = mat ? We : Ws;
    const float* __restrict__ bias = mat ? be : bs;
    float* __restrict__ dst        = mat ? E_t : S_t;

    const int n0 = blockIdx.x * 64;
    const int m0 = blockIdx.y * 64;
    const int tid = threadIdx.x;
    const int tm = tid >> 4, tn = tid & 15;

    __shared__ float As[16][65];
    __shared__ float Bs[16][65];

    float acc[4][4] = {};

    const int rx = tid >> 2;        // 0..63  X row
    const int kq = (tid & 3) * 4;   // 0,4,8,12  X k-group
    const int kw = tid >> 4;        // 0..15  W row
    const int cw = (tid & 15) * 4;  // W col group

    for (int k0 = 0; k0 < HIN_; k0 += 16) {
        float4 xv = *reinterpret_cast<const float4*>(
            &X[(size_t)(m0 + rx) * HIN_ + k0 + kq]);
        As[kq + 0][rx] = xv.x;
        As[kq + 1][rx] = xv.y;
        As[kq + 2][rx] = xv.z;
        As[kq + 3][rx] = xv.w;
        #pragma unroll
        for (int i = 0; i < 4; ++i) {
            int n = n0 + cw + i;
            Bs[kw][cw + i] = (n < TOT_) ? W[(size_t)(k0 + kw) * TOT_ + n] : 0.f;
        }
        __syncthreads();
        #pragma unroll
        for (int kk = 0; kk < 16; ++kk) {
            float av[4], bv[4];
            #pragma unroll
            for (int i = 0; i < 4; ++i) av[i] = As[kk][tm * 4 + i];
            #pragma unroll
            for (int j = 0; j < 4; ++j) bv[j] = Bs[kk][tn * 4 + j];
            #pragma unroll
            for (int i = 0; i < 4; ++i)
                #pragma unroll
                for (int j = 0; j < 4; ++j)
                    acc[i][j] += av[i] * bv[j];
        }
        __syncthreads();
    }

    #pragma unroll
    for (int i = 0; i < 4; ++i) {
        int m = m0 + tm * 4 + i;
        int bb = m >> 9, l = m & (L_ - 1);
        #pragma unroll
        for (int j = 0; j < 4; ++j) {
            int n = n0 + tn * 4 + j;
            if (n < TOT_) {
                int e = n / D_, d = n - e * D_;
                dst[(((size_t)(bb * NE1_ + e)) * L_ + l) * D_ + d] = acc[i][j] + bias[n];
            }
        }
    }
}

// ---------------- Kernel B: RoPE in-place on e<16 ----------------
__global__ void rope_kernel(float* __restrict__ S_t, float* __restrict__ E_t)
{
    int idx = blockIdx.x * blockDim.x + threadIdx.x;
    const int total = 2 * B_ * ENT_ * L_ * (D_ / 2);  // 819200
    if (idx >= total) return;
    int p   = idx % 25;
    int l   = (idx / 25) % L_;
    int e   = (idx / (25 * L_)) % ENT_;
    int bb  = (idx / (25 * L_ * ENT_)) % B_;
    int mat = idx / (25 * L_ * ENT_ * B_);
    float* ptr = mat ? E_t : S_t;
    size_t base = (((size_t)(bb * NE1_ + e)) * L_ + l) * D_ + 2 * p;
    // inv_freq = 10000^(-2p/50) = exp(-p * 2*ln(10000)/50)
    float invf = expf(-0.36841361487904737f * (float)p);
    float ang = (float)l * invf;
    float s, c;
    sincosf(ang, &s, &c);
    float x0 = ptr[base], x1 = ptr[base + 1];
    ptr[base]     = x0 * c - x1 * s;
    ptr[base + 1] = x1 * c + x0 * s;
}

// ---------------- Kernel C: conj diagonal ----------------
__global__ void conj_diag_kernel(const float* __restrict__ S_t,
                                 const float* __restrict__ E_t,
                                 float* __restrict__ cd)
{
    int t = blockIdx.x * blockDim.x + threadIdx.x;
    if (t >= B_ * (L_ - 1)) return;
    int bb = t / (L_ - 1);
    int i  = t % (L_ - 1);
    const float* cs = &S_t[(((size_t)(bb * NE1_ + ENT_)) * L_ + i) * D_];
    const float* ce = &E_t[(((size_t)(bb * NE1_ + ENT_)) * L_ + i + 1) * D_];
    float s = 0.f;
    #pragma unroll 10
    for (int d = 0; d < D_; ++d) s += cs[d] * ce[d];
    cd[t] = s * SCALE_;
}

// ---------------- Kernel D1: mask reduction (k-chunked) ----------------
// fm_part[kc][b][i][j] = sum_{k in chunk} cd[b][k] * mask[k][i][j]
__global__ __launch_bounds__(256) void mask_reduce(
    const float* __restrict__ mask, const float* __restrict__ cd,
    float* __restrict__ fm_part)
{
    const int i  = blockIdx.x;
    const int kc = blockIdx.y;
    const int k0 = kc * 128;
    const int nk = min(511 - k0, 128);
    const int tid = threadIdx.x;

    __shared__ float cdl[2][128];
    if (tid < 128) {
        cdl[0][tid] = (tid < nk) ? cd[k0 + tid] : 0.f;
        cdl[1][tid] = (tid < nk) ? cd[(L_ - 1) + k0 + tid] : 0.f;
    }
    __syncthreads();

    const int j = tid * 2;
    float f00 = 0.f, f01 = 0.f, f10 = 0.f, f11 = 0.f;
    const float* mp = &mask[((size_t)k0 * L_ + i) * L_ + j];
    #pragma unroll 4
    for (int k = 0; k < nk; ++k) {
        float2 m2 = *reinterpret_cast<const float2*>(mp);
        float c0 = cdl[0][k], c1 = cdl[1][k];
        f00 += c0 * m2.x; f01 += c0 * m2.y;
        f10 += c1 * m2.x; f11 += c1 * m2.y;
        mp += (size_t)L_ * L_;
    }
    *reinterpret_cast<float2*>(
        &fm_part[(((size_t)(kc * 2 + 0)) * L_ + i) * L_ + j]) = make_float2(f00, f01);
    *reinterpret_cast<float2*>(
        &fm_part[(((size_t)(kc * 2 + 1)) * L_ + i) * L_ + j]) = make_float2(f10, f11);
}

// ---------------- Kernel D2: scores + mask add ----------------
// out[b][i][j][e] = SCALE * dot(q[b,e,i,:], k[b,e,j,:]) + fm[b,i,j]
// block: 16x16 (i,j) tile for one b, all 16 e in 2 LDS phases of 8 e.
#define QROW 52                // padded row (floats)
#define QEP  (16 * QROW + 4)   // per-e stride with extra pad: 836
__global__ __launch_bounds__(256) void scores_kernel(
    const float* __restrict__ S_t, const float* __restrict__ E_t,
    const float* __restrict__ fm_part, float* __restrict__ out)
{
    const int j0 = blockIdx.x * 16;
    const int i0 = blockIdx.y * 16;
    const int bb = blockIdx.z;
    const int tid = threadIdx.x;

    __shared__ float qs[8 * QEP];
    __shared__ float ks[8 * QEP];
    __shared__ float fml[16][16];

    {   // fm tile: sum the 4 partials
        int il = tid >> 4, jl = tid & 15;
        float s = 0.f;
        #pragma unroll
        for (int kc = 0; kc < 4; ++kc)
            s += fm_part[(((size_t)(kc * 2 + bb)) * L_ + i0 + il) * L_ + j0 + jl];
        fml[il][jl] = s;
    }

    const int e    = tid & 7;
    const int tile = tid >> 3;          // 0..31
    const int it   = (tile & 3) * 4;    // i offset
    const int jt   = (tile >> 2) * 2;   // j offset

    for (int ph = 0; ph < 2; ++ph) {
        __syncthreads();
        for (int idx = tid; idx < 8 * 16 * D_; idx += 256) {
            int ee  = idx / (16 * D_);
            int rem = idx % (16 * D_);
            int il = rem / D_, d = rem % D_;
            qs[ee * QEP + il * QROW + d] =
                S_t[(((size_t)(bb * NE1_ + ph * 8 + ee)) * L_ + i0 + il) * D_ + d];
            ks[ee * QEP + il * QROW + d] =
                E_t[(((size_t)(bb * NE1_ + ph * 8 + ee)) * L_ + j0 + il) * D_ + d];
        }
        __syncthreads();

        float acc[4][2] = {};
        for (int d = 0; d < D_; d += 2) {
            float2 qv[4], kv[2];
            #pragma unroll
            for (int ii = 0; ii < 4; ++ii)
                qv[ii] = *reinterpret_cast<const float2*>(&qs[e * QEP + (it + ii) * QROW + d]);
            #pragma unroll
            for (int jj = 0; jj < 2; ++jj)
                kv[jj] = *reinterpret_cast<const float2*>(&ks[e * QEP + (jt + jj) * QROW + d]);
            #pragma unroll
            for (int ii = 0; ii < 4; ++ii)
                #pragma unroll
                for (int jj = 0; jj < 2; ++jj)
                    acc[ii][jj] += qv[ii].x * kv[jj].x + qv[ii].y * kv[jj].y;
        }

        const int ea = ph * 8 + e;
        #pragma unroll
        for (int ii = 0; ii < 4; ++ii) {
            int i = it + ii;
            #pragma unroll
            for (int jj = 0; jj < 2; ++jj) {
                int j = jt + jj;
                out[(((size_t)(bb * L_ + i0 + i)) * L_ + j0 + j) * ENT_ + ea] =
                    SCALE_ * acc[ii][jj] + fml[i][j];
            }
        }
    }
}

// ---------------- launcher ----------------
extern "C" void kernel_launch(void* const* d_in, const int* in_sizes, int n_in,
                              void* d_out, int out_size, void* d_ws, size_t ws_size,
                              hipStream_t stream)
{
    const float* X    = (const float*)d_in[0];  // (2,512,1024)
    const float* mask = (const float*)d_in[1];  // (511,512,512)
    const float* Ws   = (const float*)d_in[2];  // (1024,850)
    const float* bs   = (const float*)d_in[3];  // (850)
    const float* We   = (const float*)d_in[4];  // (1024,850)
    const float* be   = (const float*)d_in[5];  // (850)
    float* out = (float*)d_out;

    float* w   = (float*)d_ws;
    float* S_t = w + OFF_S;
    float* E_t = w + OFF_E;
    float* cd  = w + OFF_CD;
    float* fmp = w + OFF_FM;

    // A: projections -> [b][e][l][d]
    gemm_proj<<<dim3(14, 16, 2), 256, 0, stream>>>(X, Ws, bs, We, be, S_t, E_t);
    // B: RoPE in-place on entities 0..15
    rope_kernel<<<3200, 256, 0, stream>>>(S_t, E_t);
    // C: conj diagonal
    conj_diag_kernel<<<4, 256, 0, stream>>>(S_t, E_t, cd);
    // D1: mask reduction partials
    mask_reduce<<<dim3(512, 4), 256, 0, stream>>>(mask, cd, fmp);
    // D2: scores + mask add
    scores_kernel<<<dim3(32, 32, 2), 256, 0, stream>>>(S_t, E_t, fmp, out);
}